// Round 3
// baseline (589.391 us; speedup 1.0000x reference)
//
#include <hip/hip_runtime.h>

// ---------------------------------------------------------------------------
// SpGAT: x@W0+b0 -> 8x GAT heads (concat 512) -> GAT(512->64) -> softmax.
// R4: aggregate xp (256 B/edge, all 8 heads at once) then per-head GEMM.
// R6: head scores via MFMA GEMM s16 = xp @ [was||wad]^T.
// R10: agg_xp 1 wave/node batched weights; v_readlane broadcasts; exp2.
// R11: rank-based CSR (1 returning-atomic pass + scan + atomic-free place).
// R12 (this round):
//   * deg striped to 16 sub-counters/node (one 64B line per node): per-line
//     atomic chains 256 -> ~16. off16[node][16] precomputed in finalize so
//     placement stays atomic-free.
//   * fuse1 = edge_rank + xp-GEMM in ONE dispatch (blockIdx split): the
//     atomic pass (0.5% VALU, 11% HBM) hides under independent MFMA work.
//   * fuse2 = edge_place + s16-GEMM (both ready after scan).
// ---------------------------------------------------------------------------

using bf16x8 = __bf16 __attribute__((ext_vector_type(8)));
using f32x4  = float  __attribute__((ext_vector_type(4)));

__device__ __forceinline__ unsigned short f2bf(float f) {
    __bf16 h = (__bf16)f;                       // fptrunc, RNE
    return __builtin_bit_cast(unsigned short, h);
}
__device__ __forceinline__ float bflo(unsigned int u) {
    return __builtin_bit_cast(float, u << 16);
}
__device__ __forceinline__ float bfhi(unsigned int u) {
    return __builtin_bit_cast(float, u & 0xffff0000u);
}
__device__ __forceinline__ float bfs(unsigned short u) {
    return __builtin_bit_cast(float, (unsigned)u << 16);
}
__device__ __forceinline__ int rdlane_i(int v, int l) {
    return __builtin_amdgcn_readlane(v, l);
}
__device__ __forceinline__ float rdlane_f(float v, int l) {
    return __builtin_bit_cast(float, __builtin_amdgcn_readlane(__builtin_bit_cast(int, v), l));
}
__device__ __forceinline__ float exp2fast(float x) {
#if __has_builtin(__builtin_amdgcn_exp2f)
    return __builtin_amdgcn_exp2f(x);
#else
    return exp2f(x);
#endif
}

#define ALPHA_NEG 0.2f
#define LOG2E 1.44269504088896340736f
#define CHUNK 20000

// --------------------------- merged pack kernel ----------------------------
// blocks 0..63: W0t; 64..319: Ballt; 320..447: Wendt; 448..451: Bscore
__global__ void pack_all(const float* __restrict__ W0, const float* __restrict__ Wh,
                         const float* __restrict__ We, const float* __restrict__ ah,
                         unsigned short* __restrict__ W0t, unsigned short* __restrict__ Ballt,
                         unsigned short* __restrict__ Wendt, unsigned short* __restrict__ Bscore) {
    int b = blockIdx.x, t = threadIdx.x;
    if (b < 64) {                               // W0 [128k][128n] -> [n][k]
        int idx = b * 256 + t;
        int n = idx >> 7, k = idx & 127;
        W0t[n * 128 + k] = f2bf(W0[k * 128 + n]);
    } else if (b < 320) {                       // Wh [8][128k][64f] -> [(h*64+f)][k]
        int idx = (b - 64) * 256 + t;
        int c = idx >> 7, k = idx & 127;
        int h = c >> 6, f = c & 63;
        Ballt[idx] = f2bf(Wh[(h * 128 + k) * 64 + f]);
    } else if (b < 448) {                       // We [512k][64n] -> [n][k]
        int idx = (b - 320) * 256 + t;
        int n = idx >> 9, k = idx & 511;
        Wendt[idx] = f2bf(We[k * 64 + n]);
    } else {                                    // Bscore [16][128], prescaled log2e
        int idx = (b - 448) * 256 + t;
        if (idx < 1024) {
            int h = idx >> 7, k = idx & 127;
            float s = 0.f, d = 0.f;
            for (int f = 0; f < 64; f++) {
                float wv = Wh[(h * 128 + k) * 64 + f];
                s += wv * ah[h * 128 + f];
                d += wv * ah[h * 128 + 64 + f];
            }
            Bscore[h * 128 + k] = f2bf(s * LOG2E);
            Bscore[(8 + h) * 128 + k] = f2bf(d * LOG2E);
        }
    }
}

// ------------------------------- GEMM core ---------------------------------
template <int BM, int BN, int K, int WM, int WN, int MT, int NT,
          bool AF32, bool BIAS, bool OBF16, bool ELU, bool BATCHZ>
__device__ __forceinline__ void gemm_core(const void* __restrict__ Ap,
                                          const unsigned short* __restrict__ Bt,
                                          const float* __restrict__ bias,
                                          void* __restrict__ Cp, int M,
                                          int lda, int ldc, int bx, int bz) {
    constexpr int LDK = 40;                    // pad 32 -> 40 shorts (80B rows, 16B-aligned)
    __shared__ unsigned short As[BM * LDK];
    __shared__ unsigned short Bs[BN * LDK];
    const int t = threadIdx.x;
    const long m0 = (long)bx * BM;
    const long n0 = 0;                         // all our launches use grid.y == 1
    const int abase = BATCHZ ? bz * K : 0;
    const unsigned short* Btz = BATCHZ ? Bt + (size_t)bz * BN * K : Bt;
    const long cbase = BATCHZ ? (long)bz * BN : 0;
    const int wave = t >> 6, lane = t & 63;
    const int wm = wave / WN, wn = wave % WN;
    const int lrow = lane & 15, lq = lane >> 4;

    f32x4 acc[MT][NT];
#pragma unroll
    for (int a = 0; a < MT; a++)
#pragma unroll
        for (int b = 0; b < NT; b++) acc[a][b] = (f32x4)0.0f;

    for (int kt = 0; kt < K / 32; kt++) {
        const int k0 = kt * 32;
        if constexpr (AF32) {
            const float* A = (const float*)Ap;
#pragma unroll
            for (int it = 0; it < BM * 8 / 256; it++) {
                int L = t + 256 * it;
                int row = L >> 3, kc = (L & 7) * 4;
                long gr = m0 + row;
                float4 v = make_float4(0.f, 0.f, 0.f, 0.f);
                if (gr < M) v = *(const float4*)&A[gr * lda + abase + k0 + kc];
                unsigned int lo = (unsigned)f2bf(v.x) | ((unsigned)f2bf(v.y) << 16);
                unsigned int hi = (unsigned)f2bf(v.z) | ((unsigned)f2bf(v.w) << 16);
                *(uint2*)&As[row * LDK + kc] = make_uint2(lo, hi);
            }
        } else {
            const unsigned short* A = (const unsigned short*)Ap;
#pragma unroll
            for (int it = 0; it < BM * 4 / 256; it++) {
                int L = t + 256 * it;
                int row = L >> 2, kc = (L & 3) * 8;
                long gr = m0 + row;
                uint4 v = make_uint4(0u, 0u, 0u, 0u);
                if (gr < M) v = *(const uint4*)&A[gr * lda + abase + k0 + kc];
                *(uint4*)&As[row * LDK + kc] = v;
            }
        }
#pragma unroll
        for (int it = 0; it < (BN * 4 + 255) / 256; it++) {
            int L = t + 256 * it;
            if (L < BN * 4) {
                int row = L >> 2, kc = (L & 3) * 8;
                *(uint4*)&Bs[row * LDK + kc] = *(const uint4*)&Btz[(n0 + row) * K + k0 + kc];
            }
        }
        __syncthreads();

        bf16x8 af[MT], bfr[NT];
#pragma unroll
        for (int mt = 0; mt < MT; mt++)
            af[mt] = *(const bf16x8*)&As[((wm * MT + mt) * 16 + lrow) * LDK + lq * 8];
#pragma unroll
        for (int nt = 0; nt < NT; nt++)
            bfr[nt] = *(const bf16x8*)&Bs[((wn * NT + nt) * 16 + lrow) * LDK + lq * 8];
#pragma unroll
        for (int mt = 0; mt < MT; mt++)
#pragma unroll
            for (int nt = 0; nt < NT; nt++)
                acc[mt][nt] = __builtin_amdgcn_mfma_f32_16x16x32_bf16(af[mt], bfr[nt],
                                                                     acc[mt][nt], 0, 0, 0);
        __syncthreads();
    }

#pragma unroll
    for (int mt = 0; mt < MT; mt++) {
        long rbase = m0 + (wm * MT + mt) * 16 + lq * 4;
#pragma unroll
        for (int nt = 0; nt < NT; nt++) {
            long col = cbase + n0 + (wn * NT + nt) * 16 + lrow;
            float bv = 0.f;
            if constexpr (BIAS) bv = bias[col];
#pragma unroll
            for (int r = 0; r < 4; r++) {
                long row = rbase + r;
                if (row < M) {
                    float v = acc[mt][nt][r] + bv;
                    if constexpr (ELU) v = v > 0.f ? v : __expf(v) - 1.0f;
                    if constexpr (OBF16)
                        ((unsigned short*)Cp)[row * ldc + col] = f2bf(v);
                    else
                        ((float*)Cp)[row * ldc + col] = v;
                }
            }
        }
    }
}

template <int BM, int BN, int K, int WM, int WN, int MT, int NT,
          bool AF32, bool BIAS, bool OBF16, bool ELU, bool BATCHZ>
__launch_bounds__(256)
__global__ void gemm_mfma(const void* __restrict__ Ap, const unsigned short* __restrict__ Bt,
                          const float* __restrict__ bias, void* __restrict__ Cp, int M,
                          int lda, int ldc) {
    gemm_core<BM, BN, K, WM, WN, MT, NT, AF32, BIAS, OBF16, ELU, BATCHZ>(
        Ap, Bt, bias, Cp, M, lda, ldc, blockIdx.x, blockIdx.z);
}

// --------------- fused: CSR edge pass + independent GEMM (R12) -------------
// MODE 0: blocks [0,eb) do rank[i]=atomicAdd(&deg16[src*16+(i&15)],1).
// MODE 1: blocks [0,eb) do dstp[off16[src*16+(i&15)]+rank[i]] = dst.
// Blocks [eb, eb+gm) run the GEMM (edge blocks first: they're the long pole).
template <int BM, int BN, int K, int WM, int WN, int MT, int NT,
          bool AF32, bool BIAS, bool OBF16, bool ELU, int MODE>
__launch_bounds__(256)
__global__ void fused_gemm_edge(const void* __restrict__ Ap,
                                const unsigned short* __restrict__ Bt,
                                const float* __restrict__ bias, void* __restrict__ Cp,
                                int M, int lda, int ldc,
                                const int* __restrict__ src, const int* __restrict__ dst,
                                int* __restrict__ tab,      // deg16 (MODE0) / off16 (MODE1)
                                int* __restrict__ rank, int* __restrict__ dstp,
                                int E, int eb) {
    if ((int)blockIdx.x < eb) {
        int i = blockIdx.x * 256 + threadIdx.x;
        if (i < E) {
            int s = src[i];
            int slot = (s << 4) + (i & 15);
            if constexpr (MODE == 0) {
                rank[i] = atomicAdd(&tab[slot], 1);
            } else {
                dstp[tab[slot] + rank[i]] = dst[i];
            }
        }
        return;
    }
    gemm_core<BM, BN, K, WM, WN, MT, NT, AF32, BIAS, OBF16, ELU, false>(
        Ap, Bt, bias, Cp, M, lda, ldc, blockIdx.x - eb, 0);
}

// ---------------------- CSR scan (striped counters) ------------------------
#define SCAN_BS 256
__global__ void scan_blocks(const int* __restrict__ deg16, int* __restrict__ incl,
                            int* __restrict__ partials, int n) {
    __shared__ int s[SCAN_BS];
    int t = threadIdx.x, i = blockIdx.x * SCAN_BS + t;
    int v = 0;
    if (i < n) {
        const int4* q = (const int4*)&deg16[(size_t)i * 16];
        int4 a = q[0], b = q[1], c = q[2], d = q[3];
        v = a.x + a.y + a.z + a.w + b.x + b.y + b.z + b.w +
            c.x + c.y + c.z + c.w + d.x + d.y + d.z + d.w;
    }
    s[t] = v; __syncthreads();
    for (int off = 1; off < SCAN_BS; off <<= 1) {
        int add = (t >= off) ? s[t - off] : 0;
        __syncthreads();
        s[t] += add;
        __syncthreads();
    }
    if (i < n) incl[i] = s[t];
    if (t == SCAN_BS - 1) partials[blockIdx.x] = s[t];
}
__global__ void scan_partials(int* __restrict__ partials, int nb) {  // 1 block, 512 thr
    __shared__ int s[512];
    int t = threadIdx.x;
    int v = (t < nb) ? partials[t] : 0;
    s[t] = v; __syncthreads();
    for (int off = 1; off < 512; off <<= 1) {
        int add = (t >= off) ? s[t - off] : 0;
        __syncthreads();
        s[t] += add;
        __syncthreads();
    }
    if (t < nb) partials[t] = s[t] - v;   // exclusive block offset
}
// row_ptr + per-(node,sub) base offsets (off16 = row_ptr + intra-node prefix)
__global__ void finalize_rowptr(const int* __restrict__ deg16, const int* __restrict__ incl,
                                const int* __restrict__ partials, int* __restrict__ row_ptr,
                                int* __restrict__ off16, int n, int E) {
    int i = blockIdx.x * 256 + threadIdx.x;
    if (i < n) {
        const int4* q = (const int4*)&deg16[(size_t)i * 16];
        int dg[16];
        *(int4*)&dg[0]  = q[0]; *(int4*)&dg[4]  = q[1];
        *(int4*)&dg[8]  = q[2]; *(int4*)&dg[12] = q[3];
        int tot = 0;
#pragma unroll
        for (int s = 0; s < 16; s++) tot += dg[s];
        int base = incl[i] - tot + partials[i / SCAN_BS];
        row_ptr[i] = base;
        int o[16];
        int run = base;
#pragma unroll
        for (int s = 0; s < 16; s++) { o[s] = run; run += dg[s]; }
        int4* w = (int4*)&off16[(size_t)i * 16];
        w[0] = *(int4*)&o[0];  w[1] = *(int4*)&o[4];
        w[2] = *(int4*)&o[8];  w[3] = *(int4*)&o[12];
    } else if (i == n) {
        row_ptr[n] = E;
    }
}

// ---------------- 8-head xp aggregation: 1 wave per node (R10) -------------
// Lane owns cols {2*lane, 2*lane+1} of the 128-col xp row, for ALL 8 heads
// (acc[8][2]). Edges processed in groups of 8:
//   lane = edge-slot(lane>>3) x head(lane&7): ONE dstp load, ONE s16 load,
//   ONE v_exp instr covers 8 edges x 8 heads of weights.
//   Per edge: one dword gather (wave = full 256B row once), v_readlane
//   broadcasts w into SGPRs for 16 v_fmac. Rowsums fall out per-lane
//   (lane&7 = head), 3 shfl_xor at node end.
__global__ void agg_xp(const int* __restrict__ row_ptr, const int* __restrict__ dstp,
                       const float* __restrict__ s16,
                       const unsigned short* __restrict__ xp, unsigned short* __restrict__ z,
                       int n0, int n1) {
    int t = threadIdx.x, wave = t >> 6, lane = t & 63;
    int i = n0 + blockIdx.x * 4 + wave;
    if (i >= n1) return;
    int e0 = __builtin_amdgcn_readfirstlane(row_ptr[i]);
    int e1 = __builtin_amdgcn_readfirstlane(row_ptr[i + 1]);
    const int hl = lane & 7, sub8 = lane >> 3;
    const int voff = lane << 1;                 // shorts: byte offset lane*4
    float ssv = s16[(size_t)i * 16 + hl];
    float acc[16];
#pragma unroll
    for (int c = 0; c < 16; c++) acc[c] = 0.f;
    float rsl = 0.f;

    for (int p = e0; p < e1; p += 8) {
        int idx = p + sub8;
        int cl = idx < e1 ? idx : e1 - 1;       // clamp (valid since e0<e1 here)
        int jv = dstp[cl];                      // 8 distinct j's across the wave
        float sc = s16[(size_t)(unsigned)jv * 16 + 8 + hl];
        float s = ssv + sc;
        s = fmaxf(s, ALPHA_NEG * s);            // leaky_relu (scores prescaled log2e)
        float wv = (idx < e1) ? exp2fast(-s) : 0.f;
        rsl += wv;
        int nem = e1 - p;                       // wave-uniform group count
        unsigned xv[8];
#pragma unroll
        for (int u = 0; u < 8; u++) {
            if (u < nem) {
                int ju = rdlane_i(jv, u * 8);   // SGPR j -> scalar base addressing
                xv[u] = *(const unsigned*)&xp[(size_t)(unsigned)ju * 128 + voff];
            }
        }
#pragma unroll
        for (int u = 0; u < 8; u++) {
            if (u < nem) {
                float lo = bflo(xv[u]), hi = bfhi(xv[u]);
#pragma unroll
                for (int h = 0; h < 8; h++) {
                    float wh = rdlane_f(wv, u * 8 + h);   // SGPR operand for fmac
                    acc[2 * h]     += wh * lo;
                    acc[2 * h + 1] += wh * hi;
                }
            }
        }
    }

    // rowsum per head: sum lanes with equal (lane&7)
    rsl += __shfl_xor(rsl, 8, 64);
    rsl += __shfl_xor(rsl, 16, 64);
    rsl += __shfl_xor(rsl, 32, 64);
    float inv = 1.0f / (rsl + 1e-16f);
    size_t zb = (size_t)(i - n0) * 1024 + voff;
#pragma unroll
    for (int h = 0; h < 8; h++) {
        float ih = rdlane_f(inv, h);
        unsigned pw = (unsigned)f2bf(acc[2 * h] * ih) |
                      ((unsigned)f2bf(acc[2 * h + 1] * ih) << 16);
        *(unsigned*)&z[zb + h * 128] = pw;
    }
}

// ----------------------------- final-layer scores --------------------------
__global__ void scores2(const unsigned short* __restrict__ h2b, const float* __restrict__ ae,
                        float* __restrict__ ss2, float* __restrict__ sd2, int n) {
    int t = threadIdx.x, wave = t >> 6, lane = t & 63;
    int i = blockIdx.x * 4 + wave;
    if (i >= n) return;
    float v = bfs(h2b[(size_t)i * 64 + lane]);
    float a = v * ae[lane];
    float b = v * ae[64 + lane];
    for (int d = 32; d > 0; d >>= 1) {
        a += __shfl_xor(a, d, 64);
        b += __shfl_xor(b, d, 64);
    }
    if (lane == 0) { ss2[i] = a * LOG2E; sd2[i] = b * LOG2E; }  // prescale for exp2
}

// --------------------- final aggregation + row softmax ---------------------
// Wave per node. Edge chunk of 64: lane L computes weight for edge base+L
// (one exp per edge). Broadcast (w,j) via v_readlane (uniform index, SGPR
// result feeds fmac + scalar row base) -- no ds_bpermute. 8-deep unroll for
// MLP. Rowsum butterfly deferred to one pass per node. (R10)
__global__ void agg_final(const int* __restrict__ row_ptr, const int* __restrict__ dstp,
                          const float* __restrict__ ss2, const float* __restrict__ sd2,
                          const unsigned short* __restrict__ h2b, float* __restrict__ out,
                          int n) {
    int t = threadIdx.x, wave = t >> 6, lane = t & 63;
    int i = blockIdx.x * 4 + wave;
    if (i >= n) return;
    int e0 = __builtin_amdgcn_readfirstlane(row_ptr[i]);
    int e1 = __builtin_amdgcn_readfirstlane(row_ptr[i + 1]);
    float ssrc = ss2[i];
    float acc = 0.f, rsl = 0.f;
    for (int base = e0; base < e1; base += 64) {
        int cnt = e1 - base; if (cnt > 64) cnt = 64;
        int jv = 0; float wv = 0.f;
        if (lane < cnt) {
            jv = dstp[base + lane];
            float sc = ssrc + sd2[jv];
            sc = fmaxf(sc, ALPHA_NEG * sc);     // prescaled log2e
            wv = exp2fast(-sc);
        }
        rsl += wv;
        int q = 0;
        for (; q + 8 <= cnt; q += 8) {
            float vv[8], ww[8];
#pragma unroll
            for (int u = 0; u < 8; u++) {
                int j = rdlane_i(jv, q + u);    // SGPR row index
                vv[u] = bfs(h2b[((size_t)(unsigned)j << 6) + lane]);
                ww[u] = rdlane_f(wv, q + u);    // SGPR weight
            }
#pragma unroll
            for (int u = 0; u < 8; u++) acc += ww[u] * vv[u];
        }
        for (; q < cnt; q++) {
            int j = rdlane_i(jv, q);
            float w = rdlane_f(wv, q);
            acc += w * bfs(h2b[((size_t)(unsigned)j << 6) + lane]);
        }
    }
    float rs = rsl;
    for (int d = 32; d > 0; d >>= 1) rs += __shfl_xor(rs, d, 64);
    float o = acc / (rs + 1e-16f);
    float m = o;
    for (int d = 32; d > 0; d >>= 1) m = fmaxf(m, __shfl_xor(m, d, 64));
    float e = __expf(o - m);
    float s = e;
    for (int d = 32; d > 0; d >>= 1) s += __shfl_xor(s, d, 64);
    out[(size_t)i * 64 + lane] = e / s;
}

// ------------------------------- launcher ----------------------------------
extern "C" void kernel_launch(void* const* d_in, const int* in_sizes, int n_in,
                              void* d_out, int out_size, void* d_ws, size_t ws_size,
                              hipStream_t stream) {
    const float* x  = (const float*)d_in[0];
    const int* edges = (const int*)d_in[1];
    const float* W0 = (const float*)d_in[2];
    const float* b0 = (const float*)d_in[3];
    const float* Wh = (const float*)d_in[4];
    const float* ah = (const float*)d_in[5];
    const float* We = (const float*)d_in[6];
    const float* ae = (const float*)d_in[7];
    float* dout = (float*)d_out;

    const int Nn = in_sizes[0] / 128;   // 100000
    const int E  = in_sizes[1] / 2;     // 1600000
    const int* src = edges;
    const int* dst = edges + E;

    char* p = (char*)d_ws;
    auto alloc = [&](size_t bytes) -> char* {
        char* r = p;
        p += (bytes + 255) & ~(size_t)255;
        return r;
    };
    unsigned short* W0t   = (unsigned short*)alloc(128 * 128 * 2);
    unsigned short* Ballt = (unsigned short*)alloc(512 * 128 * 2);
    unsigned short* Wendt = (unsigned short*)alloc((size_t)64 * 512 * 2);
    unsigned short* Bscore = (unsigned short*)alloc(16 * 128 * 2);
    int* deg16   = (int*)alloc((size_t)Nn * 16 * 4);
    int* off16   = (int*)alloc((size_t)Nn * 16 * 4);
    int* incl    = (int*)alloc((size_t)Nn * 4);
    int* part    = (int*)alloc(512 * 4);
    int* row_ptr = (int*)alloc((size_t)(Nn + 1) * 4);
    int* dstp    = (int*)alloc((size_t)E * 4);
    float* s16   = (float*)alloc((size_t)Nn * 16 * 4);
    float* ss2   = (float*)alloc((size_t)Nn * 4);
    float* sd2   = (float*)alloc((size_t)Nn * 4);
    unsigned short* xp = (unsigned short*)alloc((size_t)Nn * 128 * 2);
    unsigned short* z  = (unsigned short*)alloc((size_t)CHUNK * 1024 * 2); // h2b aliases
    unsigned short* hcat = (unsigned short*)alloc((size_t)Nn * 512 * 2);
    unsigned short* h2b = (unsigned short*)z;   // [N,64] bf16 = 12.8 MB << z
    int* rank = (int*)hcat;             // E ints = 6.4 MB; hcat dead until chunk loop

    size_t needed = (size_t)(p - (char*)d_ws);
    if (needed > ws_size) return;       // diagnostic guard

    const int gm = (Nn + 127) / 128;
    const int nScanB = (Nn + SCAN_BS - 1) / SCAN_BS;
    const int eb = (E + 255) / 256;     // edge blocks

    hipMemsetAsync(deg16, 0, (size_t)Nn * 16 * 4, stream);
    pack_all<<<452, 256, 0, stream>>>(W0, Wh, We, ah, W0t, Ballt, Wendt, Bscore);

    // fuse1: edge_rank (striped) + xp = bf16(x @ W0 + b0)
    fused_gemm_edge<128, 128, 128, 2, 2, 4, 4, true, true, true, false, 0>
        <<<eb + gm, 256, 0, stream>>>(x, W0t, b0, xp, Nn, 128, 128,
                                      src, dst, deg16, rank, dstp, E, eb);

    scan_blocks<<<nScanB, 256, 0, stream>>>(deg16, incl, part, Nn);
    scan_partials<<<1, 512, 0, stream>>>(part, nScanB);
    finalize_rowptr<<<(Nn + 256) / 256, 256, 0, stream>>>(deg16, incl, part, row_ptr,
                                                          off16, Nn, E);

    // fuse2: edge_place (atomic-free) + s16[N,16] = xp @ Bscore^T
    fused_gemm_edge<128, 16, 128, 4, 1, 2, 1, false, false, false, false, 1>
        <<<eb + gm, 256, 0, stream>>>(xp, Bscore, nullptr, s16, Nn, 128, 16,
                                      src, dst, off16, rank, dstp, E, eb);

    // chunked: z = normalized xp-aggregation; hcat = ELU(z_h @ W_h) per head
    for (int c0 = 0; c0 < Nn; c0 += CHUNK) {
        int c1 = min(c0 + CHUNK, Nn);
        int Mc = c1 - c0;
        agg_xp<<<(Mc + 3) / 4, 256, 0, stream>>>(row_ptr, dstp, s16, xp, z, c0, c1);
        gemm_mfma<128, 64, 128, 4, 1, 2, 4, false, false, true, true, true>
            <<<dim3((Mc + 127) / 128, 1, 8), 256, 0, stream>>>(
                z, Ballt, nullptr, hcat + (size_t)c0 * 512, Mc, 1024, 512);
    }

    // h2b = bf16(hcat @ W_end)  [N,64]   (aliases z, now dead)
    gemm_mfma<128, 64, 512, 4, 1, 2, 4, false, false, true, false, false>
        <<<dim3(gm, 1), 256, 0, stream>>>(hcat, Wendt, nullptr, h2b, Nn, 512, 64);

    scores2<<<(Nn + 3) / 4, 256, 0, stream>>>(h2b, ae, ss2, sd2, Nn);
    agg_final<<<(Nn + 3) / 4, 256, 0, stream>>>(row_ptr, dstp, ss2, sd2, h2b, dout, Nn);
}

// Round 4
// 560.342 us; speedup vs baseline: 1.0518x; 1.0518x over previous
//
#include <hip/hip_runtime.h>

// ---------------------------------------------------------------------------
// SpGAT: x@W0+b0 -> 8x GAT heads (concat 512) -> GAT(512->64) -> softmax.
// R4: aggregate xp (256 B/edge, all 8 heads at once) then per-head GEMM.
// R6: head scores via MFMA GEMM s16 = xp @ [was||wad]^T.
// R10: agg_xp 1 wave/node batched weights; v_readlane broadcasts; exp2.
// R13 (this round): CSR build with ZERO global atomics (R11/R12 showed
//   1.6M returning device atomics = flat ~68us, fusion can't hide it).
//   Two-level counting sort, LDS atomics only:
//     csr_hist:    per-block LDS hist of 512 coarse buckets (src>>8).
//     csr_scan:    1 block: per-bucket block-prefix + 512-wide scan.
//     csr_scatter: LDS cursors per block (disjoint ranges) -> (src,dst)
//                  pairs binned into coarse spans. No atomics.
//     csr_build:   block per bucket: LDS 256-hist + scan -> row_ptr,
//                  place dstp. Replaces old scan_* kernels too.
//   GEMMs reverted to standalone dispatches (R12 fusion = no overlap,
//   occupancy poison).
// ---------------------------------------------------------------------------

using bf16x8 = __bf16 __attribute__((ext_vector_type(8)));
using f32x4  = float  __attribute__((ext_vector_type(4)));

__device__ __forceinline__ unsigned short f2bf(float f) {
    __bf16 h = (__bf16)f;                       // fptrunc, RNE
    return __builtin_bit_cast(unsigned short, h);
}
__device__ __forceinline__ float bflo(unsigned int u) {
    return __builtin_bit_cast(float, u << 16);
}
__device__ __forceinline__ float bfhi(unsigned int u) {
    return __builtin_bit_cast(float, u & 0xffff0000u);
}
__device__ __forceinline__ float bfs(unsigned short u) {
    return __builtin_bit_cast(float, (unsigned)u << 16);
}
__device__ __forceinline__ int rdlane_i(int v, int l) {
    return __builtin_amdgcn_readlane(v, l);
}
__device__ __forceinline__ float rdlane_f(float v, int l) {
    return __builtin_bit_cast(float, __builtin_amdgcn_readlane(__builtin_bit_cast(int, v), l));
}
__device__ __forceinline__ float exp2fast(float x) {
#if __has_builtin(__builtin_amdgcn_exp2f)
    return __builtin_amdgcn_exp2f(x);
#else
    return exp2f(x);
#endif
}

#define ALPHA_NEG 0.2f
#define LOG2E 1.44269504088896340736f
#define CHUNK 20000
#define TILE 4096                               // edges per csr block
#define VPT 16                                  // TILE / 256

// --------------------------- merged pack kernel ----------------------------
// blocks 0..63: W0t; 64..319: Ballt; 320..447: Wendt; 448..451: Bscore
__global__ void pack_all(const float* __restrict__ W0, const float* __restrict__ Wh,
                         const float* __restrict__ We, const float* __restrict__ ah,
                         unsigned short* __restrict__ W0t, unsigned short* __restrict__ Ballt,
                         unsigned short* __restrict__ Wendt, unsigned short* __restrict__ Bscore) {
    int b = blockIdx.x, t = threadIdx.x;
    if (b < 64) {                               // W0 [128k][128n] -> [n][k]
        int idx = b * 256 + t;
        int n = idx >> 7, k = idx & 127;
        W0t[n * 128 + k] = f2bf(W0[k * 128 + n]);
    } else if (b < 320) {                       // Wh [8][128k][64f] -> [(h*64+f)][k]
        int idx = (b - 64) * 256 + t;
        int c = idx >> 7, k = idx & 127;
        int h = c >> 6, f = c & 63;
        Ballt[idx] = f2bf(Wh[(h * 128 + k) * 64 + f]);
    } else if (b < 448) {                       // We [512k][64n] -> [n][k]
        int idx = (b - 320) * 256 + t;
        int n = idx >> 9, k = idx & 511;
        Wendt[idx] = f2bf(We[k * 64 + n]);
    } else {                                    // Bscore [16][128], prescaled log2e
        int idx = (b - 448) * 256 + t;
        if (idx < 1024) {
            int h = idx >> 7, k = idx & 127;
            float s = 0.f, d = 0.f;
            for (int f = 0; f < 64; f++) {
                float wv = Wh[(h * 128 + k) * 64 + f];
                s += wv * ah[h * 128 + f];
                d += wv * ah[h * 128 + 64 + f];
            }
            Bscore[h * 128 + k] = f2bf(s * LOG2E);
            Bscore[(8 + h) * 128 + k] = f2bf(d * LOG2E);
        }
    }
}

// ------------------- CSR build: two-level counting sort --------------------
// Coarse bucket = src >> 8 (256 nodes each). hb layout: [blk][512].
__global__ void csr_hist(const int* __restrict__ src, int* __restrict__ hb, int E) {
    __shared__ int h[512];
    int t = threadIdx.x, blk = blockIdx.x;
    h[t] = 0; h[t + 256] = 0;
    __syncthreads();
    int base = blk * TILE + t;
#pragma unroll
    for (int v = 0; v < VPT; v++) {
        int e = base + v * 256;
        if (e < E) atomicAdd(&h[src[e] >> 8], 1);
    }
    __syncthreads();
    hb[blk * 512 + t] = h[t];
    hb[blk * 512 + t + 256] = h[t + 256];
}

// 1 block, 512 threads. Thread t owns bucket t: running prefix over blocks
// (counts -> block-local offsets), then 512-wide scan for bucket bases.
__global__ void csr_scan(int* __restrict__ hb, int* __restrict__ bkt_base, int ablk) {
    __shared__ int s[512];
    int t = threadIdx.x;
    int run = 0;
    for (int b0 = 0; b0 < ablk; b0 += 8) {
        int vv[8];
#pragma unroll
        for (int u = 0; u < 8; u++) {
            int blk = b0 + u;
            vv[u] = (blk < ablk) ? hb[blk * 512 + t] : 0;
        }
#pragma unroll
        for (int u = 0; u < 8; u++) {
            int blk = b0 + u;
            if (blk < ablk) hb[blk * 512 + t] = run;
            run += vv[u];
        }
    }
    s[t] = run;
    __syncthreads();
    for (int off = 1; off < 512; off <<= 1) {
        int add = (t >= off) ? s[t - off] : 0;
        __syncthreads();
        s[t] += add;
        __syncthreads();
    }
    bkt_base[t] = s[t] - run;                   // exclusive base; [nbkt] == E
}

// Atomic-free global scatter: each block's per-bucket range is disjoint.
__global__ void csr_scatter(const int* __restrict__ src, const int* __restrict__ dst,
                            const int* __restrict__ hb, const int* __restrict__ bkt_base,
                            int2* __restrict__ pairs, int E) {
    __shared__ int cur[512];
    int t = threadIdx.x, blk = blockIdx.x;
    cur[t]       = hb[blk * 512 + t]       + bkt_base[t];
    cur[t + 256] = hb[blk * 512 + t + 256] + bkt_base[t + 256];
    __syncthreads();
    int base = blk * TILE + t;
#pragma unroll
    for (int v = 0; v < VPT; v++) {
        int e = base + v * 256;
        if (e < E) {
            int sv = src[e], dv = dst[e];
            int pos = atomicAdd(&cur[sv >> 8], 1);   // LDS atomic
            pairs[pos] = make_int2(sv, dv);
        }
    }
}

// Block per coarse bucket: fine hist over 256 nodes, LDS scan -> row_ptr,
// then place dst into final CSR order.
__global__ void csr_build(const int2* __restrict__ pairs, const int* __restrict__ bkt_base,
                          int* __restrict__ row_ptr, int* __restrict__ dstp, int n) {
    __shared__ int h[256];
    __shared__ int sc[256];
    int t = threadIdx.x, b = blockIdx.x;
    int e0 = bkt_base[b], e1 = bkt_base[b + 1];
    h[t] = 0;
    __syncthreads();
    for (int e = e0 + t; e < e1; e += 256) atomicAdd(&h[pairs[e].x & 255], 1);
    __syncthreads();
    int v = h[t];
    sc[t] = v;
    __syncthreads();
    for (int off = 1; off < 256; off <<= 1) {
        int add = (t >= off) ? sc[t - off] : 0;
        __syncthreads();
        sc[t] += add;
        __syncthreads();
    }
    int excl = sc[t] - v;
    int gid = (b << 8) + t;
    if (gid <= n) row_ptr[gid] = e0 + excl;     // gid==n lands here too (== E)
    h[t] = excl;                                // reuse as cursor
    __syncthreads();
    for (int e = e0 + t; e < e1; e += 256) {
        int2 pr = pairs[e];
        int pos = atomicAdd(&h[pr.x & 255], 1); // LDS atomic
        dstp[e0 + pos] = pr.y;
    }
}

// ------------------------------- MFMA GEMM ---------------------------------
template <int BM, int BN, int K, int WM, int WN, int MT, int NT,
          bool AF32, bool BIAS, bool OBF16, bool ELU, bool BATCHZ>
__launch_bounds__(256)
__global__ void gemm_mfma(const void* __restrict__ Ap, const unsigned short* __restrict__ Bt,
                          const float* __restrict__ bias, void* __restrict__ Cp, int M,
                          int lda, int ldc) {
    constexpr int LDK = 40;                    // pad 32 -> 40 shorts (80B rows, 16B-aligned)
    __shared__ unsigned short As[BM * LDK];
    __shared__ unsigned short Bs[BN * LDK];
    const int t = threadIdx.x;
    const long m0 = (long)blockIdx.x * BM;
    const long n0 = (long)blockIdx.y * BN;
    const int abase = BATCHZ ? blockIdx.z * K : 0;
    const unsigned short* Btz = BATCHZ ? Bt + (size_t)blockIdx.z * BN * K : Bt;
    const long cbase = BATCHZ ? (long)blockIdx.z * BN : 0;
    const int wave = t >> 6, lane = t & 63;
    const int wm = wave / WN, wn = wave % WN;
    const int lrow = lane & 15, lq = lane >> 4;

    f32x4 acc[MT][NT];
#pragma unroll
    for (int a = 0; a < MT; a++)
#pragma unroll
        for (int b = 0; b < NT; b++) acc[a][b] = (f32x4)0.0f;

    for (int kt = 0; kt < K / 32; kt++) {
        const int k0 = kt * 32;
        if constexpr (AF32) {
            const float* A = (const float*)Ap;
#pragma unroll
            for (int it = 0; it < BM * 8 / 256; it++) {
                int L = t + 256 * it;
                int row = L >> 3, kc = (L & 7) * 4;
                long gr = m0 + row;
                float4 v = make_float4(0.f, 0.f, 0.f, 0.f);
                if (gr < M) v = *(const float4*)&A[gr * lda + abase + k0 + kc];
                unsigned int lo = (unsigned)f2bf(v.x) | ((unsigned)f2bf(v.y) << 16);
                unsigned int hi = (unsigned)f2bf(v.z) | ((unsigned)f2bf(v.w) << 16);
                *(uint2*)&As[row * LDK + kc] = make_uint2(lo, hi);
            }
        } else {
            const unsigned short* A = (const unsigned short*)Ap;
#pragma unroll
            for (int it = 0; it < BM * 4 / 256; it++) {
                int L = t + 256 * it;
                int row = L >> 2, kc = (L & 3) * 8;
                long gr = m0 + row;
                uint4 v = make_uint4(0u, 0u, 0u, 0u);
                if (gr < M) v = *(const uint4*)&A[gr * lda + abase + k0 + kc];
                *(uint4*)&As[row * LDK + kc] = v;
            }
        }
#pragma unroll
        for (int it = 0; it < (BN * 4 + 255) / 256; it++) {
            int L = t + 256 * it;
            if (L < BN * 4) {
                int row = L >> 2, kc = (L & 3) * 8;
                *(uint4*)&Bs[row * LDK + kc] = *(const uint4*)&Btz[(n0 + row) * K + k0 + kc];
            }
        }
        __syncthreads();

        bf16x8 af[MT], bfr[NT];
#pragma unroll
        for (int mt = 0; mt < MT; mt++)
            af[mt] = *(const bf16x8*)&As[((wm * MT + mt) * 16 + lrow) * LDK + lq * 8];
#pragma unroll
        for (int nt = 0; nt < NT; nt++)
            bfr[nt] = *(const bf16x8*)&Bs[((wn * NT + nt) * 16 + lrow) * LDK + lq * 8];
#pragma unroll
        for (int mt = 0; mt < MT; mt++)
#pragma unroll
            for (int nt = 0; nt < NT; nt++)
                acc[mt][nt] = __builtin_amdgcn_mfma_f32_16x16x32_bf16(af[mt], bfr[nt],
                                                                     acc[mt][nt], 0, 0, 0);
        __syncthreads();
    }

#pragma unroll
    for (int mt = 0; mt < MT; mt++) {
        long rbase = m0 + (wm * MT + mt) * 16 + lq * 4;
#pragma unroll
        for (int nt = 0; nt < NT; nt++) {
            long col = cbase + n0 + (wn * NT + nt) * 16 + lrow;
            float bv = 0.f;
            if constexpr (BIAS) bv = bias[col];
#pragma unroll
            for (int r = 0; r < 4; r++) {
                long row = rbase + r;
                if (row < M) {
                    float v = acc[mt][nt][r] + bv;
                    if constexpr (ELU) v = v > 0.f ? v : __expf(v) - 1.0f;
                    if constexpr (OBF16)
                        ((unsigned short*)Cp)[row * ldc + col] = f2bf(v);
                    else
                        ((float*)Cp)[row * ldc + col] = v;
                }
            }
        }
    }
}

// ---------------- 8-head xp aggregation: 1 wave per node (R10) -------------
// Lane owns cols {2*lane, 2*lane+1} of the 128-col xp row, for ALL 8 heads
// (acc[8][2]). Edges processed in groups of 8:
//   lane = edge-slot(lane>>3) x head(lane&7): ONE dstp load, ONE s16 load,
//   ONE v_exp instr covers 8 edges x 8 heads of weights.
//   Per edge: one dword gather (wave = full 256B row once), v_readlane
//   broadcasts w into SGPRs for 16 v_fmac. Rowsums fall out per-lane
//   (lane&7 = head), 3 shfl_xor at node end.
__global__ void agg_xp(const int* __restrict__ row_ptr, const int* __restrict__ dstp,
                       const float* __restrict__ s16,
                       const unsigned short* __restrict__ xp, unsigned short* __restrict__ z,
                       int n0, int n1) {
    int t = threadIdx.x, wave = t >> 6, lane = t & 63;
    int i = n0 + blockIdx.x * 4 + wave;
    if (i >= n1) return;
    int e0 = __builtin_amdgcn_readfirstlane(row_ptr[i]);
    int e1 = __builtin_amdgcn_readfirstlane(row_ptr[i + 1]);
    const int hl = lane & 7, sub8 = lane >> 3;
    const int voff = lane << 1;                 // shorts: byte offset lane*4
    float ssv = s16[(size_t)i * 16 + hl];
    float acc[16];
#pragma unroll
    for (int c = 0; c < 16; c++) acc[c] = 0.f;
    float rsl = 0.f;

    for (int p = e0; p < e1; p += 8) {
        int idx = p + sub8;
        int cl = idx < e1 ? idx : e1 - 1;       // clamp (valid since e0<e1 here)
        int jv = dstp[cl];                      // 8 distinct j's across the wave
        float sc = s16[(size_t)(unsigned)jv * 16 + 8 + hl];
        float s = ssv + sc;
        s = fmaxf(s, ALPHA_NEG * s);            // leaky_relu (scores prescaled log2e)
        float wv = (idx < e1) ? exp2fast(-s) : 0.f;
        rsl += wv;
        int nem = e1 - p;                       // wave-uniform group count
        unsigned xv[8];
#pragma unroll
        for (int u = 0; u < 8; u++) {
            if (u < nem) {
                int ju = rdlane_i(jv, u * 8);   // SGPR j -> scalar base addressing
                xv[u] = *(const unsigned*)&xp[(size_t)(unsigned)ju * 128 + voff];
            }
        }
#pragma unroll
        for (int u = 0; u < 8; u++) {
            if (u < nem) {
                float lo = bflo(xv[u]), hi = bfhi(xv[u]);
#pragma unroll
                for (int h = 0; h < 8; h++) {
                    float wh = rdlane_f(wv, u * 8 + h);   // SGPR operand for fmac
                    acc[2 * h]     += wh * lo;
                    acc[2 * h + 1] += wh * hi;
                }
            }
        }
    }

    // rowsum per head: sum lanes with equal (lane&7)
    rsl += __shfl_xor(rsl, 8, 64);
    rsl += __shfl_xor(rsl, 16, 64);
    rsl += __shfl_xor(rsl, 32, 64);
    float inv = 1.0f / (rsl + 1e-16f);
    size_t zb = (size_t)(i - n0) * 1024 + voff;
#pragma unroll
    for (int h = 0; h < 8; h++) {
        float ih = rdlane_f(inv, h);
        unsigned pw = (unsigned)f2bf(acc[2 * h] * ih) |
                      ((unsigned)f2bf(acc[2 * h + 1] * ih) << 16);
        *(unsigned*)&z[zb + h * 128] = pw;
    }
}

// ----------------------------- final-layer scores --------------------------
__global__ void scores2(const unsigned short* __restrict__ h2b, const float* __restrict__ ae,
                        float* __restrict__ ss2, float* __restrict__ sd2, int n) {
    int t = threadIdx.x, wave = t >> 6, lane = t & 63;
    int i = blockIdx.x * 4 + wave;
    if (i >= n) return;
    float v = bfs(h2b[(size_t)i * 64 + lane]);
    float a = v * ae[lane];
    float b = v * ae[64 + lane];
    for (int d = 32; d > 0; d >>= 1) {
        a += __shfl_xor(a, d, 64);
        b += __shfl_xor(b, d, 64);
    }
    if (lane == 0) { ss2[i] = a * LOG2E; sd2[i] = b * LOG2E; }  // prescale for exp2
}

// --------------------- final aggregation + row softmax ---------------------
// Wave per node. Edge chunk of 64: lane L computes weight for edge base+L
// (one exp per edge). Broadcast (w,j) via v_readlane (uniform index, SGPR
// result feeds fmac + scalar row base) -- no ds_bpermute. 8-deep unroll for
// MLP. Rowsum butterfly deferred to one pass per node. (R10)
__global__ void agg_final(const int* __restrict__ row_ptr, const int* __restrict__ dstp,
                          const float* __restrict__ ss2, const float* __restrict__ sd2,
                          const unsigned short* __restrict__ h2b, float* __restrict__ out,
                          int n) {
    int t = threadIdx.x, wave = t >> 6, lane = t & 63;
    int i = blockIdx.x * 4 + wave;
    if (i >= n) return;
    int e0 = __builtin_amdgcn_readfirstlane(row_ptr[i]);
    int e1 = __builtin_amdgcn_readfirstlane(row_ptr[i + 1]);
    float ssrc = ss2[i];
    float acc = 0.f, rsl = 0.f;
    for (int base = e0; base < e1; base += 64) {
        int cnt = e1 - base; if (cnt > 64) cnt = 64;
        int jv = 0; float wv = 0.f;
        if (lane < cnt) {
            jv = dstp[base + lane];
            float sc = ssrc + sd2[jv];
            sc = fmaxf(sc, ALPHA_NEG * sc);     // prescaled log2e
            wv = exp2fast(-sc);
        }
        rsl += wv;
        int q = 0;
        for (; q + 8 <= cnt; q += 8) {
            float vv[8], ww[8];
#pragma unroll
            for (int u = 0; u < 8; u++) {
                int j = rdlane_i(jv, q + u);    // SGPR row index
                vv[u] = bfs(h2b[((size_t)(unsigned)j << 6) + lane]);
                ww[u] = rdlane_f(wv, q + u);    // SGPR weight
            }
#pragma unroll
            for (int u = 0; u < 8; u++) acc += ww[u] * vv[u];
        }
        for (; q < cnt; q++) {
            int j = rdlane_i(jv, q);
            float w = rdlane_f(wv, q);
            acc += w * bfs(h2b[((size_t)(unsigned)j << 6) + lane]);
        }
    }
    float rs = rsl;
    for (int d = 32; d > 0; d >>= 1) rs += __shfl_xor(rs, d, 64);
    float o = acc / (rs + 1e-16f);
    float m = o;
    for (int d = 32; d > 0; d >>= 1) m = fmaxf(m, __shfl_xor(m, d, 64));
    float e = __expf(o - m);
    float s = e;
    for (int d = 32; d > 0; d >>= 1) s += __shfl_xor(s, d, 64);
    out[(size_t)i * 64 + lane] = e / s;
}

// ------------------------------- launcher ----------------------------------
extern "C" void kernel_launch(void* const* d_in, const int* in_sizes, int n_in,
                              void* d_out, int out_size, void* d_ws, size_t ws_size,
                              hipStream_t stream) {
    const float* x  = (const float*)d_in[0];
    const int* edges = (const int*)d_in[1];
    const float* W0 = (const float*)d_in[2];
    const float* b0 = (const float*)d_in[3];
    const float* Wh = (const float*)d_in[4];
    const float* ah = (const float*)d_in[5];
    const float* We = (const float*)d_in[6];
    const float* ae = (const float*)d_in[7];
    float* dout = (float*)d_out;

    const int Nn = in_sizes[0] / 128;   // 100000
    const int E  = in_sizes[1] / 2;     // 1600000
    const int* src = edges;
    const int* dst = edges + E;

    char* p = (char*)d_ws;
    auto alloc = [&](size_t bytes) -> char* {
        char* r = p;
        p += (bytes + 255) & ~(size_t)255;
        return r;
    };
    unsigned short* W0t   = (unsigned short*)alloc(128 * 128 * 2);
    unsigned short* Ballt = (unsigned short*)alloc(512 * 128 * 2);
    unsigned short* Wendt = (unsigned short*)alloc((size_t)64 * 512 * 2);
    unsigned short* Bscore = (unsigned short*)alloc(16 * 128 * 2);
    const int ablk = (E + TILE - 1) / TILE;     // csr edge blocks
    int* hist_blk = (int*)alloc((size_t)ablk * 512 * 4);
    int* bkt_base = (int*)alloc(512 * 4);
    int* row_ptr = (int*)alloc((size_t)(Nn + 1) * 4);
    int* dstp    = (int*)alloc((size_t)E * 4);
    float* s16   = (float*)alloc((size_t)Nn * 16 * 4);
    float* ss2   = (float*)alloc((size_t)Nn * 4);
    float* sd2   = (float*)alloc((size_t)Nn * 4);
    unsigned short* xp = (unsigned short*)alloc((size_t)Nn * 128 * 2);
    unsigned short* z  = (unsigned short*)alloc((size_t)CHUNK * 1024 * 2); // h2b aliases
    unsigned short* hcat = (unsigned short*)alloc((size_t)Nn * 512 * 2);
    unsigned short* h2b = (unsigned short*)z;   // [N,64] bf16 = 12.8 MB << z
    int2* pairs = (int2*)hcat;          // E int2 = 12.8 MB; hcat dead until chunk loop

    size_t needed = (size_t)(p - (char*)d_ws);
    if (needed > ws_size) return;       // diagnostic guard

    const int gm = (Nn + 127) / 128;
    const int nbkt = (Nn + 255) >> 8;   // coarse buckets (256 nodes each)

    pack_all<<<452, 256, 0, stream>>>(W0, Wh, We, ah, W0t, Ballt, Wendt, Bscore);

    // CSR build: no global atomics.
    csr_hist<<<ablk, 256, 0, stream>>>(src, hist_blk, E);
    csr_scan<<<1, 512, 0, stream>>>(hist_blk, bkt_base, ablk);
    csr_scatter<<<ablk, 256, 0, stream>>>(src, dst, hist_blk, bkt_base, pairs, E);
    csr_build<<<nbkt, 256, 0, stream>>>(pairs, bkt_base, row_ptr, dstp, Nn);

    // xp = bf16(x @ W0 + b0)
    gemm_mfma<128, 128, 128, 2, 2, 4, 4, true, true, true, false, false>
        <<<dim3(gm, 1), 256, 0, stream>>>(x, W0t, b0, xp, Nn, 128, 128);

    // s16[N,16] = xp @ Bscore^T  (cols 0..7 = src scores, 8..15 = dst scores)
    gemm_mfma<128, 16, 128, 4, 1, 2, 1, false, false, false, false, false>
        <<<dim3(gm, 1), 256, 0, stream>>>(xp, Bscore, nullptr, s16, Nn, 128, 16);

    // chunked: z = normalized xp-aggregation; hcat = ELU(z_h @ W_h) per head
    for (int c0 = 0; c0 < Nn; c0 += CHUNK) {
        int c1 = min(c0 + CHUNK, Nn);
        int Mc = c1 - c0;
        agg_xp<<<(Mc + 3) / 4, 256, 0, stream>>>(row_ptr, dstp, s16, xp, z, c0, c1);
        gemm_mfma<128, 64, 128, 4, 1, 2, 4, false, false, true, true, true>
            <<<dim3((Mc + 127) / 128, 1, 8), 256, 0, stream>>>(
                z, Ballt, nullptr, hcat + (size_t)c0 * 512, Mc, 1024, 512);
    }

    // h2b = bf16(hcat @ W_end)  [N,64]   (aliases z, now dead)
    gemm_mfma<128, 64, 512, 4, 1, 2, 4, false, false, true, false, false>
        <<<dim3(gm, 1), 256, 0, stream>>>(hcat, Wendt, nullptr, h2b, Nn, 512, 64);

    scores2<<<(Nn + 3) / 4, 256, 0, stream>>>(h2b, ae, ss2, sd2, Nn);
    agg_final<<<(Nn + 3) / 4, 256, 0, stream>>>(row_ptr, dstp, ss2, sd2, h2b, dout, Nn);
}